// Round 4
// baseline (166080.408 us; speedup 1.0000x reference)
//
#include <hip/hip_runtime.h>
#include <cstdint>

using u16 = unsigned short;
using u32 = unsigned int;

typedef __bf16 bf16x8 __attribute__((ext_vector_type(8)));
typedef float  f32x4  __attribute__((ext_vector_type(4)));

#define Bb 64
#define Ss 512
#define Hh 1024
#define WPITCH 2064          // bytes per LDS weight/h row (1032 u16)
#define SCAN_LDS 135168

__device__ __forceinline__ float b2f(u16 u) {
    u32 i = ((u32)u) << 16; float f; __builtin_memcpy(&f, &i, 4); return f;
}
__device__ __forceinline__ u16 f2b(float f) {
    u32 i; __builtin_memcpy(&i, &f, 4);
    u32 r = (i + 0x7FFFu + ((i >> 16) & 1u)) >> 16; return (u16)r;
}
__device__ __forceinline__ uint4 pack8f(const float* f) {
    u16 t[8];
#pragma unroll
    for (int j = 0; j < 8; ++j) t[j] = f2b(f[j]);
    uint4 r; __builtin_memcpy(&r, t, 16); return r;
}
// load 8 consecutive elements at element-index idx as 8 packed bf16
__device__ __forceinline__ uint4 ld8(const void* p, long idx, bool f32) {
    if (f32) {
        float tmp[8];
        *(uint4*)tmp       = *(const uint4*)((const float*)p + idx);
        *(uint4*)(tmp + 4) = *(const uint4*)((const float*)p + idx + 4);
        return pack8f(tmp);
    }
    return *(const uint4*)((const u16*)p + idx);
}
__device__ __forceinline__ float ld1(const void* p, long idx, bool f32) {
    return f32 ? ((const float*)p)[idx] : b2f(((const u16*)p)[idx]);
}
__device__ __forceinline__ float dot8(uint4 a, uint4 b) {
    const u16* pa = (const u16*)&a;
    const u16* pb = (const u16*)&b;
    float s = 0.f;
#pragma unroll
    for (int j = 0; j < 8; ++j) s += b2f(pa[j]) * b2f(pb[j]);
    return s;
}

// ---------------------------------------------------------------------------
// Detect device float dtype from a weight buffer (|w| <= 1/32 if bf16).
// flag = 1 -> buffers are float32 ; flag = 0 -> bfloat16.
// ---------------------------------------------------------------------------
__global__ void detect_dtype(const void* __restrict__ w, u32* __restrict__ flag) {
    if (threadIdx.x == 0 && blockIdx.x == 0) {
        const u16* p = (const u16*)w;
        int cnt = 0;
        for (int i = 0; i < 256; ++i) {
            float v = b2f(p[i]);
            if (v > 1.f || v < -1.f) ++cnt;
        }
        *flag = cnt ? 1u : 0u;
    }
}

// ---------------------------------------------------------------------------
// GEMM: C[m][nb+n] (+bias) = sum_k Arow(m)[k] * W[layer*2^20 + k*1024 + nb+n]
// 64x64x64 tiles, 4 waves (2x2), MFMA 16x16x32 bf16, padded LDS (pitch 144B).
// mode_in : 0 -> A row m = ((m&63)*512 + t0 + (m>>6))*1024   1 -> m*1024
// mode_out: 0 -> ((float*)C)[m*ldc + col]                (internal, no bias)
//           1 -> out[((m&63)*512 + t0 + (m>>6))*1024+col] in flag dtype (+bias)
// ---------------------------------------------------------------------------
__global__ __launch_bounds__(256) void gemm64(const void* __restrict__ A,
                                              const void* __restrict__ W,
                                              void* __restrict__ C,
                                              const void* __restrict__ bias,
                                              const u32* __restrict__ flag,
                                              int a_ext, int layer, int mode_in,
                                              int mode_out, int t0, int ldc) {
    __shared__ uint4 sA4[576];   // 64 rows x 144B
    __shared__ uint4 sW4[576];   // 64 n-rows x 144B (transposed W tile)
    char* sA = (char*)sA4;
    char* sW = (char*)sW4;

    const bool wf32 = (*flag != 0);
    const bool af32 = a_ext ? wf32 : true;
    const long wbase = (long)layer * 1048576;
    const long bbase = (long)layer * 1024;

    const int tid  = threadIdx.x;
    const int lane = tid & 63;
    const int wv   = tid >> 6;
    const int wm   = wv >> 1, wn = wv & 1;
    const int mb   = blockIdx.x * 64, nb = blockIdx.y * 64;

    const int srow = tid >> 2;        // 0..63 (A-row / W-k-row)
    const int sq   = tid & 3;         // 0..3

    long abase;
    {
        int m = mb + srow;
        abase = (mode_in == 0)
                  ? ((long)((m & 63) * Ss + t0 + (m >> 6))) * 1024
                  : (long)m * 1024;
    }

    f32x4 acc[2][2] = {};

    for (int kb = 0; kb < 1024; kb += 64) {
        __syncthreads();
        // ---- stage A tile [64][64]
        {
            uint4 va0 = ld8(A, abase + kb + sq * 8, af32);
            uint4 va1 = ld8(A, abase + kb + 32 + sq * 8, af32);
            *(uint4*)(sA + srow * 144 + sq * 16)      = va0;
            *(uint4*)(sA + srow * 144 + 64 + sq * 16) = va1;
        }
        // ---- stage W tile transposed: sW[n][k] = W[kb+k][nb+n]
        {
            uint4 vw0 = ld8(W, wbase + (long)(kb + srow) * 1024 + nb + sq * 8, wf32);
            uint4 vw1 = ld8(W, wbase + (long)(kb + srow) * 1024 + nb + 32 + sq * 8, wf32);
            u16 e0[8], e1[8];
            __builtin_memcpy(e0, &vw0, 16);
            __builtin_memcpy(e1, &vw1, 16);
#pragma unroll
            for (int j = 0; j < 8; ++j) {
                *(u16*)(sW + (sq * 8 + j) * 144 + srow * 2)      = e0[j];
                *(u16*)(sW + (32 + sq * 8 + j) * 144 + srow * 2) = e1[j];
            }
        }
        __syncthreads();
#pragma unroll
        for (int ks = 0; ks < 2; ++ks) {
            const int kby = ks * 64 + ((lane >> 4) << 4);
            bf16x8 aF[2], bF[2];
#pragma unroll
            for (int r = 0; r < 2; ++r) {
                int row = wm * 32 + r * 16 + (lane & 15);
                aF[r] = *(const bf16x8*)(sA + row * 144 + kby);
            }
#pragma unroll
            for (int c = 0; c < 2; ++c) {
                int nn = wn * 32 + c * 16 + (lane & 15);
                bF[c] = *(const bf16x8*)(sW + nn * 144 + kby);
            }
#pragma unroll
            for (int r = 0; r < 2; ++r)
#pragma unroll
                for (int c = 0; c < 2; ++c)
                    acc[r][c] = __builtin_amdgcn_mfma_f32_16x16x32_bf16(
                        aF[r], bF[c], acc[r][c], 0, 0, 0);
        }
    }

#pragma unroll
    for (int r = 0; r < 2; ++r) {
#pragma unroll
        for (int c = 0; c < 2; ++c) {
#pragma unroll
            for (int e = 0; e < 4; ++e) {
                int m   = mb + wm * 32 + r * 16 + ((lane >> 4) << 2) + e;
                int col = nb + wn * 32 + c * 16 + (lane & 15);
                float v = acc[r][c][e];
                if (mode_out == 0) {
                    ((float*)C)[(long)m * ldc + col] = v;
                } else {
                    if (bias) v += ld1(bias, bbase + col, wf32);
                    long off = ((long)((m & 63) * Ss + t0 + (m >> 6))) * 1024 + col;
                    if (wf32) ((float*)C)[off] = v;
                    else      ((u16*)C)[off]   = f2b(v);
                }
            }
        }
    }
}

// ---------------------------------------------------------------------------
// GRU scan, scalar-FMA dots, f32 h-carry in ws, bf16 operands in LDS.
// Grid: 256 WGs x 512 threads, 1 WG/CU. 4 groups x 64 WGs.
// Group g owns batches [g*16,+16); WG w owns H-columns [w*16,+16).
// ---------------------------------------------------------------------------
__global__ __launch_bounds__(512) void gru_scan(
    const void* __restrict__ Whz, const void* __restrict__ Whr,
    const void* __restrict__ Whg, const void* __restrict__ bzp,
    const void* __restrict__ brp, const void* __restrict__ bgp,
    const float* __restrict__ X,   // [CCp*64][3072] xz|xr|xg (f32)
    float* __restrict__ hc,        // [CCp][64][1024] (f32)
    float* __restrict__ hstate,    // [64][1024] (f32)
    u16* __restrict__ rhbuf,       // [4][16][1024] (bf16)
    u32* __restrict__ ctr,         // [4][CCp][2]
    const u32* __restrict__ flag,
    int layer, int first_chunk, int CCp) {
    extern __shared__ char sm[];
    char* wl  = sm;                 // 3*16*2064 = 99072
    char* hs  = sm + 99072;         // 16*2064   = 33024
    char* scG = sm + 132096;        // 2048
    char* gts = sm + 134144;        // 1024

    const bool wf32 = (*flag != 0);
    const long wbase = (long)layer * 1048576;
    const long bbase = (long)layer * 1024;
    const int tid  = threadIdx.x;
    const int grp  = blockIdx.x & 3;
    const int w    = blockIdx.x >> 2;
    const int bg0  = grp * 16;
    const int n0w  = w * 16;
    u32* ctrg = ctr + grp * (CCp * 2);
    u16* rh   = rhbuf + grp * 16 * 1024;

    // ---- pin weight slices: wl[g][n][k] = Wg[k][n0w+n]
    {
        const void* Wsrc[3] = {Whz, Whr, Whg};
        for (int g3 = 0; g3 < 3; ++g3) {
#pragma unroll
            for (int it = 0; it < 2; ++it) {
                int k = it * 512 + tid;
                uint4 v0 = ld8(Wsrc[g3], wbase + (long)k * 1024 + n0w, wf32);
                uint4 v1 = ld8(Wsrc[g3], wbase + (long)k * 1024 + n0w + 8, wf32);
                u16 e0[8], e1[8];
                __builtin_memcpy(e0, &v0, 16);
                __builtin_memcpy(e1, &v1, 16);
#pragma unroll
                for (int j = 0; j < 8; ++j) {
                    *(u16*)(wl + g3 * 33024 + j * WPITCH + k * 2)       = e0[j];
                    *(u16*)(wl + g3 * 33024 + (8 + j) * WPITCH + k * 2) = e1[j];
                }
            }
        }
    }
    const int zb    = tid >> 5;      // batch 0..15
    const int znn   = tid & 31;
    const int zgate = znn >> 4;      // 0=z, 1=r
    const int zn    = znn & 15;      // col 0..15
    const float biasZR = ld1(zgate ? brp : bzp, bbase + n0w + zn, wf32);
    const int gb = tid >> 4, gn = tid & 15;      // g-combine mapping (tid<256)
    const float biasG = (tid < 256) ? ld1(bgp, bbase + n0w + gn, wf32) : 0.f;
    // g-dot mapping: all 512 threads, half-dots
    const int db   = tid >> 5;       // batch 0..15
    const int dn   = tid & 15;       // col 0..15
    const int dh   = (tid >> 4) & 1; // half 0/1
    __syncthreads();

    for (int tc = 0; tc < CCp; ++tc) {
        const float xzr =
            X[(long)(tc * 64 + bg0 + zb) * 3072 + zgate * 1024 + n0w + zn];
        float xg = 0.f;
        if (tid < 256)
            xg = X[(long)(tc * 64 + bg0 + gb) * 3072 + 2048 + n0w + gn];

        // ---- own h(t-1) in f32 (exact carry)
        float h_own = 0.f;
        if (!(first_chunk && tc == 0)) {
            const float* hsrc0 = (tc == 0) ? hstate
                                           : (hc + (long)(tc - 1) * Bb * 1024);
            h_own = hsrc0[(long)(bg0 + zb) * 1024 + n0w + zn];
        }

        // ---- stage h(t-1) into hs[b][k] as bf16
        {
            const int row = tid >> 5;          // 0..15
            const int c32 = tid & 31;          // 32-elem chunk
            if (first_chunk && tc == 0) {
                uint4 z4 = {0, 0, 0, 0};
#pragma unroll
                for (int u = 0; u < 4; ++u)
                    *(uint4*)(hs + row * WPITCH + c32 * 64 + u * 16) = z4;
            } else {
                const float* p = ((tc == 0) ? hstate
                                            : (hc + (long)(tc - 1) * Bb * 1024)) +
                                 (long)(bg0 + row) * 1024 + c32 * 32;
#pragma unroll
                for (int u = 0; u < 4; ++u) {
                    float tmp[8];
                    *(uint4*)tmp       = *(const uint4*)(p + u * 8);
                    *(uint4*)(tmp + 4) = *(const uint4*)(p + u * 8 + 4);
                    *(uint4*)(hs + row * WPITCH + c32 * 64 + u * 16) = pack8f(tmp);
                }
            }
        }
        __syncthreads();

        // ---- z,r: full dot per thread (512 threads = 16b x 16n x 2 gates)
        float s = 0.f;
        {
            const char* hrow = hs + zb * WPITCH;
            const char* wrow = wl + zgate * 33024 + zn * WPITCH;
#pragma unroll 8
            for (int k8 = 0; k8 < 128; ++k8) {
                uint4 hv  = *(const uint4*)(hrow + k8 * 16);
                uint4 wv4 = *(const uint4*)(wrow + k8 * 16);
                s += dot8(hv, wv4);
            }
        }
        float zval = 0.f;
        {
            s += xzr + biasZR;
            float sig = 1.f / (1.f + __expf(-s));
            if (zgate == 0) zval = sig;
            else            rh[(long)zb * 1024 + n0w + zn] = f2b(sig * h_own);
        }
        __threadfence();
        __syncthreads();
        if (tid == 0) {
            __hip_atomic_fetch_add(&ctrg[tc * 2 + 0], 1u, __ATOMIC_RELEASE,
                                   __HIP_MEMORY_SCOPE_AGENT);
            while (__hip_atomic_load(&ctrg[tc * 2 + 0], __ATOMIC_ACQUIRE,
                                     __HIP_MEMORY_SCOPE_AGENT) < 64u)
                __builtin_amdgcn_s_sleep(1);
        }
        __syncthreads();
        __threadfence();

        // ---- stage full r*h into hs (bf16)
        {
            const int row = tid >> 5;
            const int c32 = tid & 31;
            const u16* p = rh + (long)row * 1024 + c32 * 32;
#pragma unroll
            for (int u = 0; u < 4; ++u) {
                uint4 v = *(const uint4*)(p + u * 8);
                *(uint4*)(hs + row * WPITCH + c32 * 64 + u * 16) = v;
            }
        }
        __syncthreads();

        // ---- g: half-dots (512 threads = 16b x 16n x 2 halves)
        {
            float sg = 0.f;
            const char* hrow = hs + db * WPITCH + dh * 1024;   // half in bytes
            const char* wrow = wl + 2 * 33024 + dn * WPITCH + dh * 1024;
#pragma unroll 8
            for (int k8 = 0; k8 < 64; ++k8) {
                uint4 hv  = *(const uint4*)(hrow + k8 * 16);
                uint4 wv4 = *(const uint4*)(wrow + k8 * 16);
                sg += dot8(hv, wv4);
            }
            *(float*)(scG + ((db * 16 + dn) * 2 + dh) * 4) = sg;
        }
        __syncthreads();
        if (tid < 256) {
            float s2 = *(const float*)(scG + (gb * 16 + gn) * 8) +
                       *(const float*)(scG + (gb * 16 + gn) * 8 + 4) +
                       xg + biasG;
            float e  = __expf(-2.f * s2);
            float gt = 2.f / (1.f + e) - 1.f;
            *(float*)(gts + (gb * 16 + gn) * 4) = gt;
        }
        __syncthreads();

        // ---- h update + publish (f32)
        if (zgate == 0) {
            float gt = *(const float*)(gts + (zb * 16 + zn) * 4);
            float hn = zval * h_own + (1.f - zval) * gt;
            hc[(long)tc * Bb * 1024 + (long)(bg0 + zb) * 1024 + n0w + zn] = hn;
            if (tc == CCp - 1)
                hstate[(long)(bg0 + zb) * 1024 + n0w + zn] = hn;
        }
        __threadfence();
        __syncthreads();
        if (tid == 0) {
            __hip_atomic_fetch_add(&ctrg[tc * 2 + 1], 1u, __ATOMIC_RELEASE,
                                   __HIP_MEMORY_SCOPE_AGENT);
            while (__hip_atomic_load(&ctrg[tc * 2 + 1], __ATOMIC_ACQUIRE,
                                     __HIP_MEMORY_SCOPE_AGENT) < 64u)
                __builtin_amdgcn_s_sleep(1);
        }
        __syncthreads();
        __threadfence();
    }
}

// ---------------------------------------------------------------------------
__global__ __launch_bounds__(256) void copy_hidden(const float* __restrict__ hstate,
                                                   void* __restrict__ out,
                                                   const u32* __restrict__ flag) {
    const bool f32o = (*flag != 0);
    int i = blockIdx.x * 256 + threadIdx.x;   // 131072 total
    int b = i >> 11, l = (i >> 10) & 1, c = i & 1023;
    float v = hstate[(long)(l * 64 + b) * 1024 + c];
    if (f32o) ((float*)out)[33554432 + i] = v;
    else      ((u16*)out)[33554432 + i]   = f2b(v);
}

// ---------------------------------------------------------------------------
extern "C" void kernel_launch(void* const* d_in, const int* in_sizes, int n_in,
                              void* d_out, int out_size, void* d_ws,
                              size_t ws_size, hipStream_t stream) {
    const void* input = d_in[0];
    const void* Wxz = d_in[1];
    const void* Whz = d_in[2];
    const void* bz  = d_in[3];
    const void* Wxr = d_in[4];
    const void* Whr = d_in[5];
    const void* br  = d_in[6];
    const void* Wxg = d_in[7];
    const void* Whg = d_in[8];
    const void* bg  = d_in[9];
    const void* Why = d_in[10];
    const void* by  = d_in[11];

    // ---- runtime chunk-size selection: footprint = 688384 + CC*1310720 B
    int CC = 2;
    {
        const size_t fixed = 688384;
        const int cand[5] = {64, 32, 16, 8, 4};
        for (int i = 0; i < 5; ++i) {
            size_t need = fixed + (size_t)cand[i] * 1310720;
            if (ws_size >= need) { CC = cand[i]; break; }
        }
    }
    const int NCHUNK = 512 / CC;

    char* ws = (char*)d_ws;
    u32*   flag = (u32*)ws;                        // [0, 256)
    u32*   ctr  = (u32*)(ws + 256);                // 32768 B -> [256, 33024)
    float* hst  = (float*)(ws + 33024);            // 524288 B [2][64][1024]
    u16*   rh   = (u16*)(ws + 557312);             // 131072 B [4][16][1024]
    float* X    = (float*)(ws + 688384);           // CC*786432 B
    float* h0c  = X   + (size_t)CC * 196608;       // CC*262144 B
    float* h1c  = h0c + (size_t)CC * 65536;       // CC*262144 B
    (void)in_sizes; (void)n_in; (void)out_size;

    hipFuncSetAttribute(reinterpret_cast<const void*>(gru_scan),
                        hipFuncAttributeMaxDynamicSharedMemorySize, SCAN_LDS);
    detect_dtype<<<1, 64, 0, stream>>>(Wxz, flag);
    hipMemsetAsync(ctr, 0, 32768, stream);

    const void* Wx[3] = {Wxz, Wxr, Wxg};
    const int ctr_per_launch = 8 * CC;             // u32s per scan launch

    for (int k = 0; k < NCHUNK; ++k) {
        int t0 = k * CC;
        // layer-0 x-projections (A = input, external dtype)
        for (int g = 0; g < 3; ++g)
            gemm64<<<dim3(CC, 16), 256, 0, stream>>>(
                input, Wx[g], X + g * 1024, nullptr, flag,
                /*a_ext=*/1, /*layer=*/0, /*mode_in=*/0, /*mode_out=*/0,
                t0, 3072);
        // layer-0 recurrence
        gru_scan<<<256, 512, SCAN_LDS, stream>>>(
            Whz, Whr, Whg, bz, br, bg, X, h0c, hst, rh,
            ctr + (size_t)(0 * NCHUNK + k) * ctr_per_launch, flag,
            /*layer=*/0, (k == 0) ? 1 : 0, CC);
        // layer-1 x-projections (A = h0c, internal f32)
        for (int g = 0; g < 3; ++g)
            gemm64<<<dim3(CC, 16), 256, 0, stream>>>(
                h0c, Wx[g], X + g * 1024, nullptr, flag,
                /*a_ext=*/0, /*layer=*/1, /*mode_in=*/1, /*mode_out=*/0,
                t0, 3072);
        // layer-1 recurrence
        gru_scan<<<256, 512, SCAN_LDS, stream>>>(
            Whz, Whr, Whg, bz, br, bg, X, h1c, hst + 65536, rh,
            ctr + (size_t)(1 * NCHUNK + k) * ctr_per_launch, flag,
            /*layer=*/1, (k == 0) ? 1 : 0, CC);
        // output projection y = h1 @ Why + by -> d_out (flag dtype)
        gemm64<<<dim3(CC, 16), 256, 0, stream>>>(
            h1c, Why, d_out, by, flag,
            /*a_ext=*/0, /*layer=*/0, /*mode_in=*/1, /*mode_out=*/1,
            t0, 1024);
    }
    copy_hidden<<<512, 256, 0, stream>>>(hst, d_out, flag);
}

// Round 5
// 94811.548 us; speedup vs baseline: 1.7517x; 1.7517x over previous
//
#include <hip/hip_runtime.h>
#include <cstdint>

using u16 = unsigned short;
using u32 = unsigned int;

typedef __bf16 bf16x8 __attribute__((ext_vector_type(8)));
typedef float  f32x4  __attribute__((ext_vector_type(4)));

#define Bb 64
#define Ss 512
#define WPITCH 2064          // bytes per LDS weight/h row (1032 u16)
#define SCAN_LDS 150528

__device__ __forceinline__ float b2f(u16 u) {
    u32 i = ((u32)u) << 16; float f; __builtin_memcpy(&f, &i, 4); return f;
}
__device__ __forceinline__ u16 f2b(float f) {
    u32 i; __builtin_memcpy(&i, &f, 4);
    u32 r = (i + 0x7FFFu + ((i >> 16) & 1u)) >> 16; return (u16)r;
}
__device__ __forceinline__ uint4 pack8f(const float* f) {
    u16 t[8];
#pragma unroll
    for (int j = 0; j < 8; ++j) t[j] = f2b(f[j]);
    uint4 r; __builtin_memcpy(&r, t, 16); return r;
}
// load 8 consecutive elements at element-index idx as 8 packed bf16
__device__ __forceinline__ uint4 ld8(const void* p, long idx, bool f32) {
    if (f32) {
        float tmp[8];
        *(uint4*)tmp       = *(const uint4*)((const float*)p + idx);
        *(uint4*)(tmp + 4) = *(const uint4*)((const float*)p + idx + 4);
        return pack8f(tmp);
    }
    return *(const uint4*)((const u16*)p + idx);
}
__device__ __forceinline__ float ld1(const void* p, long idx, bool f32) {
    return f32 ? ((const float*)p)[idx] : b2f(((const u16*)p)[idx]);
}

// ---------------------------------------------------------------------------
// Detect device float dtype from a weight buffer (|w| <= 1/32 if bf16).
// flag = 1 -> buffers are float32 ; flag = 0 -> bfloat16.
// ---------------------------------------------------------------------------
__global__ void detect_dtype(const void* __restrict__ w, u32* __restrict__ flag) {
    if (threadIdx.x == 0 && blockIdx.x == 0) {
        const u16* p = (const u16*)w;
        int cnt = 0;
        for (int i = 0; i < 256; ++i) {
            float v = b2f(p[i]);
            if (v > 1.f || v < -1.f) ++cnt;
        }
        *flag = cnt ? 1u : 0u;
    }
}

// ---------------------------------------------------------------------------
// GEMM: C[m][nb+n] (+bias) = sum_k Arow(m)[k] * W[layer*2^20 + k*1024 + nb+n]
// 64x64x64 tiles, 4 waves (2x2), MFMA 16x16x32 bf16, padded LDS (pitch 144B).
// mode_in : 0 -> A row m = ((m&63)*512 + t0 + (m>>6))*1024   1 -> m*1024
// mode_out: 0 -> ((float*)C)[m*ldc + col]                (internal, no bias)
//           1 -> out[((m&63)*512 + t0 + (m>>6))*1024+col] in flag dtype (+bias)
// ---------------------------------------------------------------------------
__global__ __launch_bounds__(256) void gemm64(const void* __restrict__ A,
                                              const void* __restrict__ W,
                                              void* __restrict__ C,
                                              const void* __restrict__ bias,
                                              const u32* __restrict__ flag,
                                              int a_ext, int layer, int mode_in,
                                              int mode_out, int t0, int ldc) {
    __shared__ uint4 sA4[576];   // 64 rows x 144B
    __shared__ uint4 sW4[576];   // 64 n-rows x 144B (transposed W tile)
    char* sA = (char*)sA4;
    char* sW = (char*)sW4;

    const bool wf32 = (*flag != 0);
    const bool af32 = a_ext ? wf32 : true;
    const long wbase = (long)layer * 1048576;
    const long bbase = (long)layer * 1024;

    const int tid  = threadIdx.x;
    const int lane = tid & 63;
    const int wv   = tid >> 6;
    const int wm   = wv >> 1, wn = wv & 1;
    const int mb   = blockIdx.x * 64, nb = blockIdx.y * 64;

    const int srow = tid >> 2;        // 0..63 (A-row / W-k-row)
    const int sq   = tid & 3;         // 0..3

    long abase;
    {
        int m = mb + srow;
        abase = (mode_in == 0)
                  ? ((long)((m & 63) * Ss + t0 + (m >> 6))) * 1024
                  : (long)m * 1024;
    }

    f32x4 acc[2][2] = {};

    for (int kb = 0; kb < 1024; kb += 64) {
        __syncthreads();
        // ---- stage A tile [64][64]
        {
            uint4 va0 = ld8(A, abase + kb + sq * 8, af32);
            uint4 va1 = ld8(A, abase + kb + 32 + sq * 8, af32);
            *(uint4*)(sA + srow * 144 + sq * 16)      = va0;
            *(uint4*)(sA + srow * 144 + 64 + sq * 16) = va1;
        }
        // ---- stage W tile transposed: sW[n][k] = W[kb+k][nb+n]
        {
            uint4 vw0 = ld8(W, wbase + (long)(kb + srow) * 1024 + nb + sq * 8, wf32);
            uint4 vw1 = ld8(W, wbase + (long)(kb + srow) * 1024 + nb + 32 + sq * 8, wf32);
            u16 e0[8], e1[8];
            __builtin_memcpy(e0, &vw0, 16);
            __builtin_memcpy(e1, &vw1, 16);
#pragma unroll
            for (int j = 0; j < 8; ++j) {
                *(u16*)(sW + (sq * 8 + j) * 144 + srow * 2)      = e0[j];
                *(u16*)(sW + (32 + sq * 8 + j) * 144 + srow * 2) = e1[j];
            }
        }
        __syncthreads();
#pragma unroll
        for (int ks = 0; ks < 2; ++ks) {
            const int kby = ks * 64 + ((lane >> 4) << 4);
            bf16x8 aF[2], bF[2];
#pragma unroll
            for (int r = 0; r < 2; ++r) {
                int row = wm * 32 + r * 16 + (lane & 15);
                aF[r] = *(const bf16x8*)(sA + row * 144 + kby);
            }
#pragma unroll
            for (int c = 0; c < 2; ++c) {
                int nn = wn * 32 + c * 16 + (lane & 15);
                bF[c] = *(const bf16x8*)(sW + nn * 144 + kby);
            }
#pragma unroll
            for (int r = 0; r < 2; ++r)
#pragma unroll
                for (int c = 0; c < 2; ++c)
                    acc[r][c] = __builtin_amdgcn_mfma_f32_16x16x32_bf16(
                        aF[r], bF[c], acc[r][c], 0, 0, 0);
        }
    }

#pragma unroll
    for (int r = 0; r < 2; ++r) {
#pragma unroll
        for (int c = 0; c < 2; ++c) {
#pragma unroll
            for (int e = 0; e < 4; ++e) {
                int m   = mb + wm * 32 + r * 16 + ((lane >> 4) << 2) + e;
                int col = nb + wn * 32 + c * 16 + (lane & 15);
                float v = acc[r][c][e];
                if (mode_out == 0) {
                    ((float*)C)[(long)m * ldc + col] = v;
                } else {
                    if (bias) v += ld1(bias, bbase + col, wf32);
                    long off = ((long)((m & 63) * Ss + t0 + (m >> 6))) * 1024 + col;
                    if (wf32) ((float*)C)[off] = v;
                    else      ((u16*)C)[off]   = f2b(v);
                }
            }
        }
    }
}

// ---------------------------------------------------------------------------
// GRU scan, MFMA GEMV + per-WG flag signaling (no central counter).
// Grid: 256 WGs x 512 threads, 1 WG/CU. 4 groups x 64 WGs.
// Group g owns batches [g*16,+16); WG w owns H-columns [w*16,+16).
// Flags: monotonic epochs, [grp][phase][par][w*16] u32 (padded cachelines).
// Exchange buffers hb16/rhb: [grp][par][16][1024] bf16, 2-deep by t parity.
// ---------------------------------------------------------------------------
__global__ __launch_bounds__(512) void gru_scan(
    const void* __restrict__ Whz, const void* __restrict__ Whr,
    const void* __restrict__ Whg, const void* __restrict__ bzp,
    const void* __restrict__ brp, const void* __restrict__ bgp,
    const float* __restrict__ X,   // [CCp*64][3072] xz|xr|xg (f32)
    float* __restrict__ hc,        // [CCp][64][1024] (f32)
    float* __restrict__ hstate,    // [64][1024] (f32), pre-offset per layer
    u16* __restrict__ hb16,        // [4][2][16][1024]
    u16* __restrict__ rhb,         // [4][2][16][1024]
    u32* __restrict__ flags,       // [4][2][2][1024]
    const u32* __restrict__ dflag,
    int layer, int first_chunk, int CCp, int eb) {
    extern __shared__ char sm[];
    char* wl   = sm;                 // 3*16*2064 = 99072
    char* hs   = sm + 99072;         // 16*2064   = 33024 -> ends 132096
    char* scZ  = sm + 132096;        // 16384 (2 gates x 8 waves x 64 x 16B)
    float* gts = (float*)(sm + 148480);   // 16x16 f32
    float* hwn = (float*)(sm + 149504);   // 16x16 f32 (h_own carry)

    const bool wf32 = (*dflag != 0);
    const long wbase = (long)layer * 1048576;
    const long bbase = (long)layer * 1024;
    const int tid  = threadIdx.x;
    const int lane = tid & 63;
    const int wv   = tid >> 6;
    const int grp  = blockIdx.x & 3;
    const int w    = blockIdx.x >> 2;
    const int bg0  = grp * 16;
    const int n0w  = w * 16;

    u16* hb  = hb16 + grp * 32768;       // [2][16][1024]
    u16* rb  = rhb  + grp * 32768;
    u32* flg = flags + grp * 4096;       // [phase][par][1024]

    // ---- pin weight slices: wl[g][col][k] = Wg[k][n0w+col]  (bf16)
    {
        const void* Wsrc[3] = {Whz, Whr, Whg};
        for (int g3 = 0; g3 < 3; ++g3) {
#pragma unroll
            for (int it = 0; it < 2; ++it) {
                int k = it * 512 + tid;
                uint4 v0 = ld8(Wsrc[g3], wbase + (long)k * 1024 + n0w, wf32);
                uint4 v1 = ld8(Wsrc[g3], wbase + (long)k * 1024 + n0w + 8, wf32);
                u16 e0[8], e1[8];
                __builtin_memcpy(e0, &v0, 16);
                __builtin_memcpy(e1, &v1, 16);
#pragma unroll
                for (int j = 0; j < 8; ++j) {
                    *(u16*)(wl + g3 * 33024 + j * WPITCH + k * 2)       = e0[j];
                    *(u16*)(wl + g3 * 33024 + (8 + j) * WPITCH + k * 2) = e1[j];
                }
            }
        }
    }
    const int zb    = tid >> 5;      // batch 0..15
    const int znn   = tid & 31;
    const int zgate = znn >> 4;      // 0=z, 1=r
    const int zn    = znn & 15;      // col 0..15
    const float biasZR = ld1(zgate ? brp : bzp, bbase + n0w + zn, wf32);
    const int gb = tid >> 4, gn = tid & 15;      // g-combine mapping (tid<256)
    const float biasG = (tid < 256) ? ld1(bgp, bbase + n0w + gn, wf32) : 0.f;
    const int srow = tid >> 5;       // staging row 0..15
    const int c32  = tid & 31;       // staging 64B chunk
    __syncthreads();

    for (int tc = 0; tc < CCp; ++tc) {
        const int par = tc & 1;
        const u32 tgt = (u32)(eb + tc + 1);

        // ---- X prefetch (safe anytime)
        const float xzr =
            X[(long)(tc * 64 + bg0 + zb) * 3072 + zgate * 1024 + n0w + zn];
        const float xg = (tid < 256)
            ? X[(long)(tc * 64 + bg0 + gb) * 3072 + 2048 + n0w + gn] : 0.f;

        // ---- stage h(t-1) into hs (bf16)
        if (tc == 0) {
            if (first_chunk) {
                uint4 z4 = {0, 0, 0, 0};
#pragma unroll
                for (int u = 0; u < 4; ++u)
                    *(uint4*)(hs + srow * WPITCH + c32 * 64 + u * 16) = z4;
            } else {
                const float* p = hstate + (long)(bg0 + srow) * 1024 + c32 * 32;
#pragma unroll
                for (int u = 0; u < 4; ++u) {
                    float tmp[8];
                    *(uint4*)tmp       = *(const uint4*)(p + u * 8);
                    *(uint4*)(tmp + 4) = *(const uint4*)(p + u * 8 + 4);
                    *(uint4*)(hs + srow * WPITCH + c32 * 64 + u * 16) = pack8f(tmp);
                }
            }
        } else {
            // wait h-flags of step tc-1 (value eb+tc)
            u32* fp = flg + 2048 + ((tc - 1) & 1) * 1024;
            if (tid < 64) {
                while (__hip_atomic_load(fp + tid * 16, __ATOMIC_ACQUIRE,
                                         __HIP_MEMORY_SCOPE_AGENT) < tgt - 1)
                    __builtin_amdgcn_s_sleep(2);
            }
            __syncthreads();
            __threadfence();
            const u16* p = hb + ((tc - 1) & 1) * 16384 + srow * 1024 + c32 * 32;
#pragma unroll
            for (int u = 0; u < 4; ++u)
                *(uint4*)(hs + srow * WPITCH + c32 * 64 + u * 16) =
                    *(const uint4*)(p + u * 8);
        }
        float h_own = (tc == 0)
            ? (first_chunk ? 0.f : hstate[(long)(bg0 + zb) * 1024 + n0w + zn])
            : hwn[zb * 16 + zn];
        __syncthreads();

        // ---- z,r MFMA GEMV: K split across 8 waves (wave wv: k in [wv*128,+128))
        {
            f32x4 accZ = {0.f, 0.f, 0.f, 0.f}, accR = {0.f, 0.f, 0.f, 0.f};
#pragma unroll
            for (int i = 0; i < 4; ++i) {
                int kby = wv * 256 + i * 64 + ((lane >> 4) << 4);
                bf16x8 aF = *(const bf16x8*)(hs + (lane & 15) * WPITCH + kby);
                bf16x8 bZ = *(const bf16x8*)(wl + (lane & 15) * WPITCH + kby);
                bf16x8 bR = *(const bf16x8*)(wl + 33024 + (lane & 15) * WPITCH + kby);
                accZ = __builtin_amdgcn_mfma_f32_16x16x32_bf16(aF, bZ, accZ, 0, 0, 0);
                accR = __builtin_amdgcn_mfma_f32_16x16x32_bf16(aF, bR, accR, 0, 0, 0);
            }
            *(f32x4*)(scZ + (wv * 64 + lane) * 16)         = accZ;
            *(f32x4*)(scZ + ((8 + wv) * 64 + lane) * 16)   = accR;
        }
        __syncthreads();

        // ---- z,r reduce -> sigmoid; r publishes r*h
        float zval = 0.f;
        {
            int ls  = ((zb >> 2) << 4) | zn;
            float s = 0.f;
#pragma unroll
            for (int ww = 0; ww < 8; ++ww)
                s += *(const float*)(scZ + ((zgate * 8 + ww) * 64 + ls) * 16 +
                                     (zb & 3) * 4);
            s += xzr + biasZR;
            float sig = 1.f / (1.f + __expf(-s));
            if (zgate == 0) zval = sig;
            else rb[par * 16384 + zb * 1024 + n0w + zn] = f2b(sig * h_own);
        }
        __syncthreads();
        if (tid == 0) {
            __threadfence();
            __hip_atomic_store(flg + par * 1024 + w * 16, tgt,
                               __ATOMIC_RELEASE, __HIP_MEMORY_SCOPE_AGENT);
        }
        // ---- wait all rh flags, stage r*h into hs
        {
            u32* fp = flg + par * 1024;
            if (tid < 64) {
                while (__hip_atomic_load(fp + tid * 16, __ATOMIC_ACQUIRE,
                                         __HIP_MEMORY_SCOPE_AGENT) < tgt)
                    __builtin_amdgcn_s_sleep(2);
            }
            __syncthreads();
            __threadfence();
            const u16* p = rb + par * 16384 + srow * 1024 + c32 * 32;
#pragma unroll
            for (int u = 0; u < 4; ++u)
                *(uint4*)(hs + srow * WPITCH + c32 * 64 + u * 16) =
                    *(const uint4*)(p + u * 8);
        }
        __syncthreads();

        // ---- g MFMA GEMV
        {
            f32x4 accG = {0.f, 0.f, 0.f, 0.f};
#pragma unroll
            for (int i = 0; i < 4; ++i) {
                int kby = wv * 256 + i * 64 + ((lane >> 4) << 4);
                bf16x8 aF = *(const bf16x8*)(hs + (lane & 15) * WPITCH + kby);
                bf16x8 bG = *(const bf16x8*)(wl + 66048 + (lane & 15) * WPITCH + kby);
                accG = __builtin_amdgcn_mfma_f32_16x16x32_bf16(aF, bG, accG, 0, 0, 0);
            }
            *(f32x4*)(scZ + (wv * 64 + lane) * 16) = accG;
        }
        __syncthreads();
        if (tid < 256) {
            int ls  = ((gb >> 2) << 4) | gn;
            float s = 0.f;
#pragma unroll
            for (int ww = 0; ww < 8; ++ww)
                s += *(const float*)(scZ + (ww * 64 + ls) * 16 + (gb & 3) * 4);
            s += xg + biasG;
            float e  = __expf(-2.f * s);
            gts[gb * 16 + gn] = 2.f / (1.f + e) - 1.f;
        }
        __syncthreads();

        // ---- h update + publish
        if (zgate == 0) {
            float gt = gts[zb * 16 + zn];
            float hn = zval * h_own + (1.f - zval) * gt;
            hc[(long)tc * 65536 + (long)(bg0 + zb) * 1024 + n0w + zn] = hn;
            hb[par * 16384 + zb * 1024 + n0w + zn] = f2b(hn);
            hwn[zb * 16 + zn] = hn;
            if (tc == CCp - 1)
                hstate[(long)(bg0 + zb) * 1024 + n0w + zn] = hn;
        }
        __syncthreads();
        if (tid == 0) {
            __threadfence();
            __hip_atomic_store(flg + 2048 + par * 1024 + w * 16, tgt,
                               __ATOMIC_RELEASE, __HIP_MEMORY_SCOPE_AGENT);
        }
    }
}

// ---------------------------------------------------------------------------
__global__ __launch_bounds__(256) void copy_hidden(const float* __restrict__ hstate,
                                                   void* __restrict__ out,
                                                   const u32* __restrict__ flag) {
    const bool f32o = (*flag != 0);
    int i = blockIdx.x * 256 + threadIdx.x;   // 131072 total
    int b = i >> 11, l = (i >> 10) & 1, c = i & 1023;
    float v = hstate[(long)(l * 64 + b) * 1024 + c];
    if (f32o) ((float*)out)[33554432 + i] = v;
    else      ((u16*)out)[33554432 + i]   = f2b(v);
}

// ---------------------------------------------------------------------------
extern "C" void kernel_launch(void* const* d_in, const int* in_sizes, int n_in,
                              void* d_out, int out_size, void* d_ws,
                              size_t ws_size, hipStream_t stream) {
    const void* input = d_in[0];
    const void* Wxz = d_in[1];
    const void* Whz = d_in[2];
    const void* bz  = d_in[3];
    const void* Wxr = d_in[4];
    const void* Whr = d_in[5];
    const void* br  = d_in[6];
    const void* Wxg = d_in[7];
    const void* Whg = d_in[8];
    const void* bg  = d_in[9];
    const void* Why = d_in[10];
    const void* by  = d_in[11];

    // ---- runtime chunk-size selection: footprint = 1114368 + CC*1310720 B
    int CC = 2;
    {
        const size_t fixed = 1114368;
        const int cand[5] = {64, 32, 16, 8, 4};
        for (int i = 0; i < 5; ++i) {
            size_t need = fixed + (size_t)cand[i] * 1310720;
            if (ws_size >= need) { CC = cand[i]; break; }
        }
    }
    const int NCHUNK = 512 / CC;

    char* ws = (char*)d_ws;
    u32*   dflag = (u32*)ws;                       // [0, 256)
    u32*   flags = (u32*)(ws + 256);               // 65536 B -> [256, 65792)
    float* hst   = (float*)(ws + 65792);           // 524288 B [2][64][1024]
    u16*   hb16  = (u16*)(ws + 590080);            // 262144 B [4][2][16][1024]
    u16*   rhb   = (u16*)(ws + 852224);            // 262144 B
    float* X     = (float*)(ws + 1114368);         // CC*786432 B
    float* h0c   = X   + (size_t)CC * 196608;      // CC*262144 B
    float* h1c   = h0c + (size_t)CC * 65536;       // CC*262144 B
    (void)in_sizes; (void)n_in; (void)out_size;

    hipFuncSetAttribute(reinterpret_cast<const void*>(gru_scan),
                        hipFuncAttributeMaxDynamicSharedMemorySize, SCAN_LDS);
    detect_dtype<<<1, 64, 0, stream>>>(Wxz, dflag);
    hipMemsetAsync(flags, 0, 65536, stream);

    const void* Wx[3] = {Wxz, Wxr, Wxg};

    for (int k = 0; k < NCHUNK; ++k) {
        int t0 = k * CC;
        // layer-0 x-projections (A = input, external dtype)
        for (int g = 0; g < 3; ++g)
            gemm64<<<dim3(CC, 16), 256, 0, stream>>>(
                input, Wx[g], X + g * 1024, nullptr, dflag,
                /*a_ext=*/1, /*layer=*/0, /*mode_in=*/0, /*mode_out=*/0,
                t0, 3072);
        // layer-0 recurrence (epoch base = (2k)*CC)
        gru_scan<<<256, 512, SCAN_LDS, stream>>>(
            Whz, Whr, Whg, bz, br, bg, X, h0c, hst, hb16, rhb, flags, dflag,
            /*layer=*/0, (k == 0) ? 1 : 0, CC, /*eb=*/(2 * k) * CC);
        // layer-1 x-projections (A = h0c, internal f32)
        for (int g = 0; g < 3; ++g)
            gemm64<<<dim3(CC, 16), 256, 0, stream>>>(
                h0c, Wx[g], X + g * 1024, nullptr, dflag,
                /*a_ext=*/0, /*layer=*/1, /*mode_in=*/1, /*mode_out=*/0,
                t0, 3072);
        // layer-1 recurrence (epoch base = (2k+1)*CC)
        gru_scan<<<256, 512, SCAN_LDS, stream>>>(
            Whz, Whr, Whg, bz, br, bg, X, h1c, hst + 65536, hb16, rhb, flags,
            dflag, /*layer=*/1, (k == 0) ? 1 : 0, CC, /*eb=*/(2 * k + 1) * CC);
        // output projection y = h1 @ Why + by -> d_out (flag dtype)
        gemm64<<<dim3(CC, 16), 256, 0, stream>>>(
            h1c, Why, d_out, by, dflag,
            /*a_ext=*/0, /*layer=*/0, /*mode_in=*/1, /*mode_out=*/1,
            t0, 1024);
    }
    copy_hidden<<<512, 256, 0, stream>>>(hst, d_out, dflag);
}

// Round 6
// 27335.345 us; speedup vs baseline: 6.0757x; 3.4685x over previous
//
#include <hip/hip_runtime.h>
#include <cstdint>

using u16 = unsigned short;
using u32 = unsigned int;
using u64 = unsigned long long;

typedef __bf16 bf16x8 __attribute__((ext_vector_type(8)));
typedef float  f32x4  __attribute__((ext_vector_type(4)));

#define WPITCH 2064          // bytes per LDS weight/h row (1032 u16)
#define SCAN_LDS 163328
#define YG_LDS   147456

__device__ __forceinline__ float b2f(u16 u) {
    u32 i = ((u32)u) << 16; float f; __builtin_memcpy(&f, &i, 4); return f;
}
__device__ __forceinline__ u16 f2b(float f) {
    u32 i; __builtin_memcpy(&i, &f, 4);
    u32 r = (i + 0x7FFFu + ((i >> 16) & 1u)) >> 16; return (u16)r;
}
__device__ __forceinline__ uint4 pack8f(const float* f) {
    u16 t[8];
#pragma unroll
    for (int j = 0; j < 8; ++j) t[j] = f2b(f[j]);
    uint4 r; __builtin_memcpy(&r, t, 16); return r;
}

// ---------------------------------------------------------------------------
// Persistent GRU scan for one layer, all 512 steps, x-projection fused.
// Grid: 256 WGs x 512 threads, 1 WG/CU. grp = blockIdx>>6 (16 batches),
// w = blockIdx&63 (16 H-columns). Recurrent weights pinned in LDS once.
// Every 4 steps each WG computes its own x-slice (16b x 4t x 48) via a
// small LDS GEMM from xin rows (layer0: input; layer1: h0 in d_out).
// Cross-WG per-step sync: per-WG epoch flags (release/acquire, no fences);
// h / r*h exchanged as bf16 via agent-scope relaxed u64 atomics, 2-deep.
// ---------------------------------------------------------------------------
__global__ __launch_bounds__(512) void gru_scan(
    const float* __restrict__ xin,   // rows (b*512+t)*1024
    const float* __restrict__ Wxz, const float* __restrict__ Wxr,
    const float* __restrict__ Wxg,
    const float* __restrict__ Whz, const float* __restrict__ Whr,
    const float* __restrict__ Whg,
    const float* __restrict__ bzp, const float* __restrict__ brp,
    const float* __restrict__ bgp,
    float* __restrict__ hout,        // [b][t][1024] f32 (d_out y-region)
    float* __restrict__ hidden,      // d_out hidden region [b][2][1024]
    u16* __restrict__ hbg,           // [4][2][16][1024] bf16
    u16* __restrict__ rbg,           // [4][2][16][1024] bf16
    u32* __restrict__ flags,         // [4][2 phase][2 par][1024]
    int layer, int eb)
{
    extern __shared__ char sm[];
    char*  wl    = sm;                    // 99072: Wh slices [3][16col][1024k]
    char*  hs    = sm + 99072;            // 33024: h / rh stage; x-phase scratch
    char*  scZ   = sm + 132096;           // 16384: GEMV partials
    float* gts   = (float*)(sm + 148480); // 1024
    float* hwn   = (float*)(sm + 149504); // 1024: h carry (f32)
    u16*   tmp16 = (u16*)(sm + 150528);   // 512: publish repack
    float* xls   = (float*)(sm + 151040); // 12288: x window [4t][16b][48]

    const long wbase = (long)layer * 1048576;
    const long bbase = (long)layer * 1024;
    const int tid  = threadIdx.x;
    const int lane = tid & 63;
    const int wv   = tid >> 6;
    const int grp  = blockIdx.x >> 6;
    const int w    = blockIdx.x & 63;
    const int bg0  = grp * 16;
    const int n0w  = w * 16;

    u64* hb64 = (u64*)hbg + grp * 8192;   // [2 par][16][256 u64]
    u64* rb64 = (u64*)rbg + grp * 8192;
    u32* flg  = flags + grp * 4096;

    // ---- pin recurrent weight slices: wl[g][col][k] = Whg[k][n0w+col]
    {
        const float* Wsrc[3] = {Whz, Whr, Whg};
        for (int g3 = 0; g3 < 3; ++g3) {
            const float* Wp = Wsrc[g3] + wbase;
#pragma unroll
            for (int it = 0; it < 2; ++it) {
                int k = it * 512 + tid;
                float t0[8], t1[8];
                *(uint4*)t0     = *(const uint4*)(Wp + (long)k*1024 + n0w);
                *(uint4*)(t0+4) = *(const uint4*)(Wp + (long)k*1024 + n0w + 4);
                *(uint4*)t1     = *(const uint4*)(Wp + (long)k*1024 + n0w + 8);
                *(uint4*)(t1+4) = *(const uint4*)(Wp + (long)k*1024 + n0w + 12);
#pragma unroll
                for (int j = 0; j < 8; ++j) {
                    *(u16*)(wl + g3*33024 + j*WPITCH + k*2)     = f2b(t0[j]);
                    *(u16*)(wl + g3*33024 + (8+j)*WPITCH + k*2) = f2b(t1[j]);
                }
            }
        }
    }
    const int zb = tid >> 5, znn = tid & 31, zgate = znn >> 4, zn = znn & 15;
    const float biasZR = (zgate ? brp : bzp)[bbase + n0w + zn];
    const int gb = tid >> 4, gn = tid & 15;
    const float biasG = (tid < 256) ? bgp[bbase + n0w + gn] : 0.f;
    const int srow = tid >> 5, c32 = tid & 31;
    // x-phase (m,n) tile ownership: tiles 0..11 (m=t/3, n=t%3)
    const int m0 = wv / 3,     n0f = wv % 3;
    const int m1 = (wv + 8)/3, n1f = (wv + 8) % 3;   // valid for wv<4
    __syncthreads();

    for (int tc = 0; tc < 512; ++tc) {
        const int par = tc & 1;
        const u32 tgt = (u32)(eb + tc + 1);

        // ================= x production (every 4 steps) =================
        if ((tc & 3) == 0) {
            char* hsA = hs;            // 64 rows x 128B
            char* hsW = hs + 8192;     // 48 rows x 128B
            f32x4 aX0 = {0,0,0,0}, aX1 = {0,0,0,0};
            for (int kt = 0; kt < 16; ++kt) {
                __syncthreads();
                {   // stage A: row r = tl*16+b ; input row (bg0+b, tc+tl)
                    int r = tid >> 3, j = tid & 7;
                    long gi = ((long)(bg0 + (r & 15)) * 512 + tc + (r >> 4)) * 1024
                              + kt*64 + j*8;
                    float tp[8];
                    *(uint4*)tp     = *(const uint4*)(xin + gi);
                    *(uint4*)(tp+4) = *(const uint4*)(xin + gi + 4);
                    *(uint4*)(hsA + r*128 + ((j*16) ^ ((r&7)<<4))) = pack8f(tp);
                }
                if (tid < 384) {   // stage W slice transposed [gam*16+n][k64]
                    int row = tid >> 3, j = tid & 7;
                    int gam = row >> 4, nn = row & 15;
                    const float* Wp = (gam==0 ? Wxz : gam==1 ? Wxr : Wxg) + wbase;
                    u16 e[8];
#pragma unroll
                    for (int q = 0; q < 8; ++q)
                        e[q] = f2b(Wp[(long)(kt*64 + j*8 + q)*1024 + n0w + nn]);
                    uint4 v; __builtin_memcpy(&v, e, 16);
                    *(uint4*)(hsW + row*128 + ((j*16) ^ ((row&7)<<4))) = v;
                }
                __syncthreads();
#pragma unroll
                for (int ks = 0; ks < 2; ++ks) {
                    int kb = ks*64 + ((lane>>4)<<4);
                    {
                        int ar = m0*16 + (lane&15), br_ = n0f*16 + (lane&15);
                        bf16x8 aF = *(const bf16x8*)(hsA + ar*128 + (kb ^ ((ar&7)<<4)));
                        bf16x8 bF = *(const bf16x8*)(hsW + br_*128 + (kb ^ ((br_&7)<<4)));
                        aX0 = __builtin_amdgcn_mfma_f32_16x16x32_bf16(aF, bF, aX0, 0,0,0);
                    }
                    if (wv < 4) {
                        int ar = m1*16 + (lane&15), br_ = n1f*16 + (lane&15);
                        bf16x8 aF = *(const bf16x8*)(hsA + ar*128 + (kb ^ ((ar&7)<<4)));
                        bf16x8 bF = *(const bf16x8*)(hsW + br_*128 + (kb ^ ((br_&7)<<4)));
                        aX1 = __builtin_amdgcn_mfma_f32_16x16x32_bf16(aF, bF, aX1, 0,0,0);
                    }
                }
            }
            __syncthreads();
#pragma unroll
            for (int q = 0; q < 4; ++q) {
                int b = ((lane>>4)<<2) + q;
                xls[m0*768 + b*48 + n0f*16 + (lane&15)] = aX0[q];
                if (wv < 4)
                    xls[m1*768 + b*48 + n1f*16 + (lane&15)] = aX1[q];
            }
            __syncthreads();
        }

        // ================= stage h(t-1) =================
        if (tc == 0) {
#pragma unroll
            for (int u = 0; u < 8; ++u)
                *(u64*)(hs + srow*WPITCH + c32*64 + u*8) = 0ull;
        } else {
            u32* fp = flg + 2048 + ((tc-1)&1)*1024;
            if (tid < 64)
                while (__hip_atomic_load(fp + tid*16, __ATOMIC_ACQUIRE,
                                         __HIP_MEMORY_SCOPE_AGENT) < tgt - 1)
                    __builtin_amdgcn_s_sleep(2);
            __syncthreads();
            const u64* src = hb64 + ((tc-1)&1)*4096 + srow*256 + c32*8;
#pragma unroll
            for (int u = 0; u < 8; ++u) {
                u64 v = __hip_atomic_load(src + u, __ATOMIC_RELAXED,
                                          __HIP_MEMORY_SCOPE_AGENT);
                *(u64*)(hs + srow*WPITCH + c32*64 + u*8) = v;
            }
        }
        const float h_own = (tc == 0) ? 0.f : hwn[zb*16 + zn];
        __syncthreads();

        // ================= z,r GEMV (K split across 8 waves) =================
        {
            f32x4 accZ = {0,0,0,0}, accR = {0,0,0,0};
#pragma unroll
            for (int i = 0; i < 4; ++i) {
                int kby = wv*256 + i*64 + ((lane>>4)<<4);
                bf16x8 aF = *(const bf16x8*)(hs + (lane&15)*WPITCH + kby);
                bf16x8 bZ = *(const bf16x8*)(wl + (lane&15)*WPITCH + kby);
                bf16x8 bR = *(const bf16x8*)(wl + 33024 + (lane&15)*WPITCH + kby);
                accZ = __builtin_amdgcn_mfma_f32_16x16x32_bf16(aF, bZ, accZ, 0,0,0);
                accR = __builtin_amdgcn_mfma_f32_16x16x32_bf16(aF, bR, accR, 0,0,0);
            }
            *(f32x4*)(scZ + (wv*64+lane)*16)       = accZ;
            *(f32x4*)(scZ + ((8+wv)*64+lane)*16)   = accR;
        }
        __syncthreads();
        float zval = 0.f;
        {
            int ls = ((zb>>2)<<4) | zn;
            float s = 0.f;
#pragma unroll
            for (int ww = 0; ww < 8; ++ww)
                s += *(const float*)(scZ + ((zgate*8+ww)*64 + ls)*16 + (zb&3)*4);
            s += xls[(tc&3)*768 + zb*48 + zgate*16 + zn] + biasZR;
            float sig = 1.f/(1.f + __expf(-s));
            if (zgate == 0) zval = sig;
            else tmp16[zb*16 + zn] = f2b(sig * h_own);
        }
        __syncthreads();
        if (tid < 64) {   // publish r*h (wave 0; vmcnt of release covers lanes)
            int b = tid >> 2, q = tid & 3;
            u16 e[4];
#pragma unroll
            for (int j = 0; j < 4; ++j) e[j] = tmp16[b*16 + q*4 + j];
            u64 v; __builtin_memcpy(&v, e, 8);
            __hip_atomic_store(rb64 + par*4096 + b*256 + (n0w>>2) + q, v,
                               __ATOMIC_RELAXED, __HIP_MEMORY_SCOPE_AGENT);
        }
        if (tid == 0)
            __hip_atomic_store(flg + par*1024 + w*16, tgt,
                               __ATOMIC_RELEASE, __HIP_MEMORY_SCOPE_AGENT);
        // wait all rh flags, stage r*h
        {
            u32* fp = flg + par*1024;
            if (tid < 64)
                while (__hip_atomic_load(fp + tid*16, __ATOMIC_ACQUIRE,
                                         __HIP_MEMORY_SCOPE_AGENT) < tgt)
                    __builtin_amdgcn_s_sleep(2);
            __syncthreads();
            const u64* src = rb64 + par*4096 + srow*256 + c32*8;
#pragma unroll
            for (int u = 0; u < 8; ++u) {
                u64 v = __hip_atomic_load(src + u, __ATOMIC_RELAXED,
                                          __HIP_MEMORY_SCOPE_AGENT);
                *(u64*)(hs + srow*WPITCH + c32*64 + u*8) = v;
            }
        }
        __syncthreads();

        // ================= g GEMV =================
        {
            f32x4 accG = {0,0,0,0};
#pragma unroll
            for (int i = 0; i < 4; ++i) {
                int kby = wv*256 + i*64 + ((lane>>4)<<4);
                bf16x8 aF = *(const bf16x8*)(hs + (lane&15)*WPITCH + kby);
                bf16x8 bG = *(const bf16x8*)(wl + 66048 + (lane&15)*WPITCH + kby);
                accG = __builtin_amdgcn_mfma_f32_16x16x32_bf16(aF, bG, accG, 0,0,0);
            }
            *(f32x4*)(scZ + (wv*64+lane)*16) = accG;
        }
        __syncthreads();
        if (tid < 256) {
            int ls = ((gb>>2)<<4) | gn;
            float s = 0.f;
#pragma unroll
            for (int ww = 0; ww < 8; ++ww)
                s += *(const float*)(scZ + (ww*64 + ls)*16 + (gb&3)*4);
            s += xls[(tc&3)*768 + gb*48 + 32 + gn] + biasG;
            float e = __expf(-2.f*s);
            gts[gb*16+gn] = 2.f/(1.f+e) - 1.f;
        }
        __syncthreads();

        // ================= h update + publish =================
        if (zgate == 0) {
            float gt = gts[zb*16+zn];
            float hn = zval*h_own + (1.f - zval)*gt;
            hout[((long)(bg0+zb)*512 + tc)*1024 + n0w + zn] = hn;
            hwn[zb*16+zn]   = hn;
            tmp16[zb*16+zn] = f2b(hn);
            if (tc == 511)
                hidden[(long)(bg0+zb)*2048 + layer*1024 + n0w + zn] = hn;
        }
        __syncthreads();
        if (tid < 64) {
            int b = tid >> 2, q = tid & 3;
            u16 e[4];
#pragma unroll
            for (int j = 0; j < 4; ++j) e[j] = tmp16[b*16 + q*4 + j];
            u64 v; __builtin_memcpy(&v, e, 8);
            __hip_atomic_store(hb64 + par*4096 + b*256 + (n0w>>2) + q, v,
                               __ATOMIC_RELAXED, __HIP_MEMORY_SCOPE_AGENT);
        }
        if (tid == 0)
            __hip_atomic_store(flg + 2048 + par*1024 + w*16, tgt,
                               __ATOMIC_RELEASE, __HIP_MEMORY_SCOPE_AGENT);
    }
}

// ---------------------------------------------------------------------------
// In-place output projection: y = h1 @ Why + by, over the h1 rows in d_out.
// 512 blocks x 256 threads; block owns 64 exclusive rows; stages them fully
// to LDS (bf16, XOR-swizzled) before writing, so in-place is safe.
// ---------------------------------------------------------------------------
__global__ __launch_bounds__(256) void ygemm(const float* __restrict__ Why,
                                             const float* __restrict__ by,
                                             float* __restrict__ y)
{
    extern __shared__ char sm[];
    char* sA = sm;            // 64 rows x 2048B (bf16 k=1024)
    char* sW = sm + 131072;   // 128 n-rows x 128B (bf16 k=64 tile)

    const int tid  = threadIdx.x;
    const int lane = tid & 63;
    const int wv   = tid >> 6;          // 4 waves
    const long r0  = (long)blockIdx.x * 64;

    // stage A = h1 rows (f32 -> bf16, swizzled)
    for (int it = 0; it < 32; ++it) {
        int c = it * 256 + tid;         // 8192 chunks of 8 elems
        int row = c >> 7, j = c & 127;
        long gi = (r0 + row) * 1024 + j * 8;
        float tp[8];
        *(uint4*)tp     = *(const uint4*)(y + gi);
        *(uint4*)(tp+4) = *(const uint4*)(y + gi + 4);
        *(uint4*)(sA + row*2048 + ((j*16) ^ ((row&7)<<4))) = pack8f(tp);
    }
    __syncthreads();

    for (int nt = 0; nt < 8; ++nt) {
        f32x4 acc[4][2] = {};
        for (int kt = 0; kt < 16; ++kt) {
            __syncthreads();
            // stage Why tile transposed: sW[n][k] = Why[kt*64+k][nt*128+n]
#pragma unroll
            for (int uu = 0; uu < 4; ++uu) {
                int u = uu * 256 + tid;       // 1024 units: 128 n x 8 jc
                int nrow = u >> 3, jc = u & 7;
                u16 e[8];
#pragma unroll
                for (int q = 0; q < 8; ++q)
                    e[q] = f2b(Why[(long)(kt*64 + jc*8 + q)*1024 + nt*128 + nrow]);
                uint4 v; __builtin_memcpy(&v, e, 16);
                *(uint4*)(sW + nrow*128 + ((jc*16) ^ ((nrow&7)<<4))) = v;
            }
            __syncthreads();
#pragma unroll
            for (int ks = 0; ks < 2; ++ks) {
                int kbA = kt*128 + ks*64 + ((lane>>4)<<4);
                int kbW = ks*64 + ((lane>>4)<<4);
#pragma unroll
                for (int cc = 0; cc < 2; ++cc) {
                    int brr = (wv*2 + cc)*16 + (lane&15);
                    bf16x8 bF = *(const bf16x8*)(sW + brr*128 + (kbW ^ ((brr&7)<<4)));
#pragma unroll
                    for (int m = 0; m < 4; ++m) {
                        int ar = m*16 + (lane&15);
                        bf16x8 aF = *(const bf16x8*)(sA + ar*2048 + (kbA ^ ((ar&7)<<4)));
                        acc[m][cc] = __builtin_amdgcn_mfma_f32_16x16x32_bf16(
                            aF, bF, acc[m][cc], 0,0,0);
                    }
                }
            }
        }
        // write y tile (+bias)
#pragma unroll
        for (int cc = 0; cc < 2; ++cc) {
            int col = nt*128 + (wv*2 + cc)*16 + (lane&15);
            float bv = by[col];
#pragma unroll
            for (int m = 0; m < 4; ++m)
#pragma unroll
                for (int q = 0; q < 4; ++q) {
                    long row = r0 + m*16 + ((lane>>4)<<2) + q;
                    y[row*1024 + col] = acc[m][cc][q] + bv;
                }
        }
    }
}

// ---------------------------------------------------------------------------
extern "C" void kernel_launch(void* const* d_in, const int* in_sizes, int n_in,
                              void* d_out, int out_size, void* d_ws,
                              size_t ws_size, hipStream_t stream) {
    const float* input = (const float*)d_in[0];
    const float* Wxz = (const float*)d_in[1];
    const float* Whz = (const float*)d_in[2];
    const float* bz  = (const float*)d_in[3];
    const float* Wxr = (const float*)d_in[4];
    const float* Whr = (const float*)d_in[5];
    const float* br  = (const float*)d_in[6];
    const float* Wxg = (const float*)d_in[7];
    const float* Whg = (const float*)d_in[8];
    const float* bg  = (const float*)d_in[9];
    const float* Why = (const float*)d_in[10];
    const float* by  = (const float*)d_in[11];
    (void)in_sizes; (void)n_in; (void)out_size; (void)ws_size;

    float* yreg   = (float*)d_out;            // [64][512][1024] h0/h1/y
    float* hidden = yreg + 33554432;          // [64][2][1024]

    char* ws = (char*)d_ws;
    u32* flags = (u32*)ws;                    //  65536 B
    u16* hbg   = (u16*)(ws + 65536);          // 262144 B
    u16* rbg   = (u16*)(ws + 327680);         // 262144 B

    hipFuncSetAttribute(reinterpret_cast<const void*>(gru_scan),
                        hipFuncAttributeMaxDynamicSharedMemorySize, SCAN_LDS);
    hipFuncSetAttribute(reinterpret_cast<const void*>(ygemm),
                        hipFuncAttributeMaxDynamicSharedMemorySize, YG_LDS);
    hipMemsetAsync(flags, 0, 65536, stream);

    // layer 0: x from input, h0 -> yreg
    gru_scan<<<256, 512, SCAN_LDS, stream>>>(
        input, Wxz, Wxr, Wxg, Whz, Whr, Whg, bz, br, bg,
        yreg, hidden, hbg, rbg, flags, /*layer=*/0, /*eb=*/0);
    // layer 1: x from h0 (read 1 window ahead), h1 overwrites yreg in place
    gru_scan<<<256, 512, SCAN_LDS, stream>>>(
        yreg, Wxz, Wxr, Wxg, Whz, Whr, Whg, bz, br, bg,
        yreg, hidden, hbg, rbg, flags, /*layer=*/1, /*eb=*/512);
    // y = h1 @ Why + by, in place over yreg
    ygemm<<<512, 256, YG_LDS, stream>>>(Why, by, yreg);
}

// Round 7
// 22022.987 us; speedup vs baseline: 7.5412x; 1.2412x over previous
//
#include <hip/hip_runtime.h>
#include <cstdint>

using u16 = unsigned short;
using u32 = unsigned int;
using u64 = unsigned long long;

typedef __bf16 bf16x8 __attribute__((ext_vector_type(8)));
typedef float  f32x4  __attribute__((ext_vector_type(4)));

#define WPITCH 2064          // bytes per LDS h row (1032 u16)
#define SCAN_LDS 105216
#define YG_LDS   147456

__device__ __forceinline__ float b2f(u16 u) {
    u32 i = ((u32)u) << 16; float f; __builtin_memcpy(&f, &i, 4); return f;
}
__device__ __forceinline__ u16 f2b(float f) {
    u32 i; __builtin_memcpy(&i, &f, 4);
    u32 r = (i + 0x7FFFu + ((i >> 16) & 1u)) >> 16; return (u16)r;
}
__device__ __forceinline__ uint4 pack8f(const float* f) {
    u16 t[8];
#pragma unroll
    for (int j = 0; j < 8; ++j) t[j] = f2b(f[j]);
    uint4 r; __builtin_memcpy(&r, t, 16); return r;
}

// ---------------------------------------------------------------------------
// Persistent GRU scan, one layer, 512 steps. 256 WGs x 512 thr, 1 WG/CU.
// grp = blockIdx>>6 (16 batches), w = blockIdx&63 (16 H-cols).
// Recurrent weights live in VGPRs as MFMA B-fragments (48 VGPR/lane).
// x-projection pipelined: 4 of 16 K-tiles per step for the NEXT 4-step
// window, double-buffered stage LDS, placed in the sync wait slots.
// Cross-WG sync: per-WG epoch flags (release/acquire); h / r*h exchanged
// as bf16 via agent-scope relaxed u64 atomics, 2-deep by parity.
// ---------------------------------------------------------------------------
__global__ __launch_bounds__(512) void gru_scan(
    const float* __restrict__ xin,   // rows (b*512+t)*1024
    const float* __restrict__ Wxz, const float* __restrict__ Wxr,
    const float* __restrict__ Wxg,
    const float* __restrict__ Whz, const float* __restrict__ Whr,
    const float* __restrict__ Whg,
    const float* __restrict__ bzp, const float* __restrict__ brp,
    const float* __restrict__ bgp,
    float* __restrict__ hout,        // [b][t][1024] f32 (d_out y-region)
    float* __restrict__ hidden,      // [b][2][1024] f32 (d_out tail)
    u16* __restrict__ hbg,           // [4][2][16][1024] bf16
    u16* __restrict__ rbg,           // [4][2][16][1024] bf16
    u32* __restrict__ flags,         // [4][2 phase][2 par][1024]
    int layer, int eb)
{
    extern __shared__ char sm[];
    char*  hs    = sm;                     // 33024: h / rh stage (pitch 2064)
    char*  scZ   = sm + 33024;             // 16384: GEMV partials
    char*  xb0   = sm + 49408;             // 14336: x-stage buf0 (A 8192 + W 6144)
    char*  xb1   = sm + 63744;             // 14336: x-stage buf1
    float* xls   = (float*)(sm + 78080);   // 24576: [2][4t][16b][48] f32
    float* gts   = (float*)(sm + 102656);  // 1024
    float* hwn   = (float*)(sm + 103680);  // 1024
    u16*   tmp16 = (u16*)(sm + 104704);    // 512

    const long wbase = (long)layer * 1048576;
    const long bbase = (long)layer * 1024;
    const int tid  = threadIdx.x;
    const int lane = tid & 63;
    const int wv   = tid >> 6;
    const int grp  = blockIdx.x >> 6;
    const int w    = blockIdx.x & 63;
    const int bg0  = grp * 16;
    const int n0w  = w * 16;

    u64* hb64 = (u64*)hbg + grp * 8192;   // [2 par][4096 u64]
    u64* rb64 = (u64*)rbg + grp * 8192;
    u32* flg  = flags + grp * 4096;

    // ---- recurrent weights -> VGPR B-fragments (k-order matches A-read)
    bf16x8 wZ[4], wR[4], wG[4];
#pragma unroll
    for (int i = 0; i < 4; ++i) {
        const int k0  = wv * 128 + i * 32 + ((lane >> 4) << 3);
        const int col = n0w + (lane & 15);
        u16 ez[8], er[8], eg[8];
#pragma unroll
        for (int j = 0; j < 8; ++j) {
            long o = wbase + (long)(k0 + j) * 1024 + col;
            ez[j] = f2b(Whz[o]); er[j] = f2b(Whr[o]); eg[j] = f2b(Whg[o]);
        }
        __builtin_memcpy(&wZ[i], ez, 16);
        __builtin_memcpy(&wR[i], er, 16);
        __builtin_memcpy(&wG[i], eg, 16);
    }

    const int zb = tid >> 5, znn = tid & 31, zgate = znn >> 4, zn = znn & 15;
    const float biasZR = (zgate ? brp : bzp)[bbase + n0w + zn];
    const int gb = tid >> 4, gn = tid & 15;
    const float biasG = (tid < 256) ? bgp[bbase + n0w + gn] : 0.f;
    // x-GEMM tile ownership (12 tiles: m=timestep 0..3, n=gate 0..2)
    const int m0 = wv / 3,       n0f = wv % 3;
    const int m1 = (wv + 8) / 3, n1f = (wv + 8) % 3;   // wv<4 only

    f32x4 aX0 = {0,0,0,0}, aX1 = {0,0,0,0};

    // ---- x-production helpers -------------------------------------------
    auto XSTAGE = [&](char* xb, int kt, int wt0) {
        char* hsA = xb; char* hsW = xb + 8192;
        {   // A slab: rows r = tl*16+b, k-tile kt (coalesced)
            int r = tid >> 3, j = tid & 7;
            long gi = ((long)(bg0 + (r & 15)) * 512 + (wt0 + (r >> 4))) * 1024
                      + kt * 64 + j * 8;
            float tp[8];
            *(uint4*)tp       = *(const uint4*)(xin + gi);
            *(uint4*)(tp + 4) = *(const uint4*)(xin + gi + 4);
            *(uint4*)(hsA + r * 128 + ((j * 16) ^ ((r & 7) << 4))) = pack8f(tp);
        }
        if (tid < 192) {   // W slab: 192 unique 64B lines, 1 per thread
            int gate = tid >> 6, k = tid & 63;
            const float* Wp = (gate == 0 ? Wxz : gate == 1 ? Wxr : Wxg)
                              + wbase + (long)(kt * 64 + k) * 1024 + n0w;
            float tp[16];
            *(uint4*)tp        = *(const uint4*)(Wp);
            *(uint4*)(tp + 4)  = *(const uint4*)(Wp + 4);
            *(uint4*)(tp + 8)  = *(const uint4*)(Wp + 8);
            *(uint4*)(tp + 12) = *(const uint4*)(Wp + 12);
#pragma unroll
            for (int nn = 0; nn < 16; ++nn) {
                int row = gate * 16 + nn;
                *(u16*)(hsW + row * 128 + ((k * 2) ^ ((row & 7) << 4))) =
                    f2b(tp[nn]);
            }
        }
    };
    auto XMFMA = [&](char* xb) {
        char* hsA = xb; char* hsW = xb + 8192;
#pragma unroll
        for (int ks = 0; ks < 2; ++ks) {
            int kb = ks * 64 + ((lane >> 4) << 4);
            {
                int ar = m0 * 16 + (lane & 15), br_ = n0f * 16 + (lane & 15);
                bf16x8 aF = *(const bf16x8*)(hsA + ar * 128 + (kb ^ ((ar & 7) << 4)));
                bf16x8 bF = *(const bf16x8*)(hsW + br_ * 128 + (kb ^ ((br_ & 7) << 4)));
                aX0 = __builtin_amdgcn_mfma_f32_16x16x32_bf16(aF, bF, aX0, 0, 0, 0);
            }
            if (wv < 4) {
                int ar = m1 * 16 + (lane & 15), br_ = n1f * 16 + (lane & 15);
                bf16x8 aF = *(const bf16x8*)(hsA + ar * 128 + (kb ^ ((ar & 7) << 4)));
                bf16x8 bF = *(const bf16x8*)(hsW + br_ * 16 * 8 + (kb ^ ((br_ & 7) << 4)));
                aX1 = __builtin_amdgcn_mfma_f32_16x16x32_bf16(aF, bF, aX1, 0, 0, 0);
            }
        }
    };
    auto XBLOCK2 = [&](int kta, int ktb, int wt0) {
        __syncthreads();
        XSTAGE(xb0, kta, wt0);
        __syncthreads();
        XMFMA(xb0);                 // overlap: stage b while mfma a
        XSTAGE(xb1, ktb, wt0);
        __syncthreads();
        XMFMA(xb1);
    };
    auto XWRITE = [&](int buf) {
#pragma unroll
        for (int q = 0; q < 4; ++q) {
            int b = ((lane >> 4) << 2) + q;
            xls[buf * 3072 + m0 * 768 + b * 48 + n0f * 16 + (lane & 15)] = aX0[q];
            if (wv < 4)
                xls[buf * 3072 + m1 * 768 + b * 48 + n1f * 16 + (lane & 15)] = aX1[q];
        }
        aX0 = (f32x4){0,0,0,0}; aX1 = (f32x4){0,0,0,0};
    };
    auto STAGE_HS = [&](const u64* src) {   // 32KB exchange -> hs, lane-contig
#pragma unroll
        for (int u = 0; u < 8; ++u) {
            int idx = u * 512 + tid;
            u64 v = __hip_atomic_load(src + idx, __ATOMIC_RELAXED,
                                      __HIP_MEMORY_SCOPE_AGENT);
            *(u64*)(hs + (idx >> 8) * WPITCH + (idx & 255) * 8) = v;
        }
    };

    // ---- prologue: window 0 (timesteps 0..3)
    for (int kt = 0; kt < 16; kt += 2) XBLOCK2(kt, kt + 1, 0);
    XWRITE(0);

    for (int tc = 0; tc < 512; ++tc) {
        const int p   = tc & 3;
        const int par = tc & 1;
        const int cur = (tc >> 2) & 1;
        const u32 tgt = (u32)(eb + tc + 1);
        const bool prod = (tc < 508);
        const int wt0 = (tc & ~3) + 4;

        if (prod) XBLOCK2(p * 4 + 0, p * 4 + 1, wt0);

        // ---- stage h(t-1)
        if (tc == 0) {
            __syncthreads();
#pragma unroll
            for (int u = 0; u < 8; ++u) {
                int idx = u * 512 + tid;
                *(u64*)(hs + (idx >> 8) * WPITCH + (idx & 255) * 8) = 0ull;
            }
        } else {
            u32* fp = flg + 2048 + ((tc - 1) & 1) * 1024;
            if (tid < 64)
                while (__hip_atomic_load(fp + tid * 16, __ATOMIC_ACQUIRE,
                                         __HIP_MEMORY_SCOPE_AGENT) < tgt - 1)
                    __builtin_amdgcn_s_sleep(2);
            __syncthreads();
            STAGE_HS(hb64 + ((tc - 1) & 1) * 4096);
        }
        const float h_own = (tc == 0) ? 0.f : hwn[zb * 16 + zn];
        __syncthreads();

        // ---- z,r GEMV (B in regs, K split across 8 waves)
        {
            f32x4 accZ = {0,0,0,0}, accR = {0,0,0,0};
#pragma unroll
            for (int i = 0; i < 4; ++i) {
                int kby = wv * 256 + i * 64 + ((lane >> 4) << 4);
                bf16x8 aF = *(const bf16x8*)(hs + (lane & 15) * WPITCH + kby);
                accZ = __builtin_amdgcn_mfma_f32_16x16x32_bf16(aF, wZ[i], accZ, 0, 0, 0);
                accR = __builtin_amdgcn_mfma_f32_16x16x32_bf16(aF, wR[i], accR, 0, 0, 0);
            }
            *(f32x4*)(scZ + (wv * 64 + lane) * 16)       = accZ;
            *(f32x4*)(scZ + ((8 + wv) * 64 + lane) * 16) = accR;
        }
        __syncthreads();
        float zval = 0.f;
        {
            int ls = ((zb >> 2) << 4) | zn;
            float s = 0.f;
#pragma unroll
            for (int ww = 0; ww < 8; ++ww)
                s += *(const float*)(scZ + ((zgate * 8 + ww) * 64 + ls) * 16 + (zb & 3) * 4);
            s += xls[cur * 3072 + p * 768 + zb * 48 + zgate * 16 + zn] + biasZR;
            float sig = 1.f / (1.f + __expf(-s));
            if (zgate == 0) zval = sig;
            else tmp16[zb * 16 + zn] = f2b(sig * h_own);
        }
        __syncthreads();
        if (tid < 64) {   // publish r*h (wave 0; release's vmcnt covers lanes)
            int b = tid >> 2, q = tid & 3;
            u16 e[4];
#pragma unroll
            for (int j = 0; j < 4; ++j) e[j] = tmp16[b * 16 + q * 4 + j];
            u64 v; __builtin_memcpy(&v, e, 8);
            __hip_atomic_store(rb64 + par * 4096 + b * 256 + (n0w >> 2) + q, v,
                               __ATOMIC_RELAXED, __HIP_MEMORY_SCOPE_AGENT);
        }
        if (tid == 0)
            __hip_atomic_store(flg + par * 1024 + w * 16, tgt,
                               __ATOMIC_RELEASE, __HIP_MEMORY_SCOPE_AGENT);

        if (prod) XBLOCK2(p * 4 + 2, p * 4 + 3, wt0);

        // ---- wait all rh flags, stage r*h
        {
            u32* fp = flg + par * 1024;
            if (tid < 64)
                while (__hip_atomic_load(fp + tid * 16, __ATOMIC_ACQUIRE,
                                         __HIP_MEMORY_SCOPE_AGENT) < tgt)
                    __builtin_amdgcn_s_sleep(2);
            __syncthreads();
            STAGE_HS(rb64 + par * 4096);
        }
        __syncthreads();

        // ---- g GEMV
        {
            f32x4 accG = {0,0,0,0};
#pragma unroll
            for (int i = 0; i < 4; ++i) {
                int kby = wv * 256 + i * 64 + ((lane >> 4) << 4);
                bf16x8 aF = *(const bf16x8*)(hs + (lane & 15) * WPITCH + kby);
                accG = __builtin_amdgcn_mfma_f32_16x16x32_bf16(aF, wG[i], accG, 0, 0, 0);
            }
            *(f32x4*)(scZ + (wv * 64 + lane) * 16) = accG;
        }
        __syncthreads();
        if (tid < 256) {
            int ls = ((gb >> 2) << 4) | gn;
            float s = 0.f;
#pragma unroll
            for (int ww = 0; ww < 8; ++ww)
                s += *(const float*)(scZ + (ww * 64 + ls) * 16 + (gb & 3) * 4);
            s += xls[cur * 3072 + p * 768 + gb * 48 + 32 + gn] + biasG;
            float e = __expf(-2.f * s);
            gts[gb * 16 + gn] = 2.f / (1.f + e) - 1.f;
        }
        __syncthreads();

        // ---- h update + publish
        if (zgate == 0) {
            float gt = gts[zb * 16 + zn];
            float hn = zval * h_own + (1.f - zval) * gt;
            hout[((long)(bg0 + zb) * 512 + tc) * 1024 + n0w + zn] = hn;
            hwn[zb * 16 + zn]   = hn;
            tmp16[zb * 16 + zn] = f2b(hn);
            if (tc == 511)
                hidden[(long)(bg0 + zb) * 2048 + layer * 1024 + n0w + zn] = hn;
        }
        __syncthreads();
        if (tid < 64) {
            int b = tid >> 2, q = tid & 3;
            u16 e[4];
#pragma unroll
            for (int j = 0; j < 4; ++j) e[j] = tmp16[b * 16 + q * 4 + j];
            u64 v; __builtin_memcpy(&v, e, 8);
            __hip_atomic_store(hb64 + par * 4096 + b * 256 + (n0w >> 2) + q, v,
                               __ATOMIC_RELAXED, __HIP_MEMORY_SCOPE_AGENT);
        }
        if (tid == 0)
            __hip_atomic_store(flg + 2048 + par * 1024 + w * 16, tgt,
                               __ATOMIC_RELEASE, __HIP_MEMORY_SCOPE_AGENT);

        if (p == 3 && prod) XWRITE(cur ^ 1);
    }
}

// ---------------------------------------------------------------------------
// In-place output projection: y = h1 @ Why + by over h1 rows in d_out.
// ---------------------------------------------------------------------------
__global__ __launch_bounds__(256) void ygemm(const float* __restrict__ Why,
                                             const float* __restrict__ by,
                                             float* __restrict__ y)
{
    extern __shared__ char sm[];
    char* sA = sm;            // 64 rows x 2048B (bf16 k=1024)
    char* sW = sm + 131072;   // 128 n-rows x 128B

    const int tid  = threadIdx.x;
    const int lane = tid & 63;
    const int wv   = tid >> 6;
    const long r0  = (long)blockIdx.x * 64;

    for (int it = 0; it < 32; ++it) {
        int c = it * 256 + tid;
        int row = c >> 7, j = c & 127;
        long gi = (r0 + row) * 1024 + j * 8;
        float tp[8];
        *(uint4*)tp       = *(const uint4*)(y + gi);
        *(uint4*)(tp + 4) = *(const uint4*)(y + gi + 4);
        *(uint4*)(sA + row * 2048 + ((j * 16) ^ ((row & 7) << 4))) = pack8f(tp);
    }
    __syncthreads();

    for (int nt = 0; nt < 8; ++nt) {
        f32x4 acc[4][2] = {};
        for (int kt = 0; kt < 16; ++kt) {
            __syncthreads();
#pragma unroll
            for (int uu = 0; uu < 4; ++uu) {
                int u = uu * 256 + tid;
                int nrow = u >> 3, jc = u & 7;
                u16 e[8];
#pragma unroll
                for (int q = 0; q < 8; ++q)
                    e[q] = f2b(Why[(long)(kt * 64 + jc * 8 + q) * 1024 + nt * 128 + nrow]);
                uint4 v; __builtin_memcpy(&v, e, 16);
                *(uint4*)(sW + nrow * 128 + ((jc * 16) ^ ((nrow & 7) << 4))) = v;
            }
            __syncthreads();
#pragma unroll
            for (int ks = 0; ks < 2; ++ks) {
                int kbA = kt * 128 + ks * 64 + ((lane >> 4) << 4);
                int kbW = ks * 64 + ((lane >> 4) << 4);
#pragma unroll
                for (int cc = 0; cc < 2; ++cc) {
                    int brr = (wv * 2 + cc) * 16 + (lane & 15);
                    bf16x8 bF = *(const bf16x8*)(sW + brr * 128 + (kbW ^ ((brr & 7) << 4)));
#pragma unroll
                    for (int m = 0; m < 4; ++m) {
                        int ar = m * 16 + (lane & 15);
                        bf16x8 aF = *(const bf16x8*)(sA + ar * 2048 + (kbA ^ ((ar & 7) << 4)));
                        acc[m][cc] = __builtin_amdgcn_mfma_f32_16x16x32_bf16(
                            aF, bF, acc[m][cc], 0, 0, 0);
                    }
                }
            }
        }
#pragma unroll
        for (int cc = 0; cc < 2; ++cc) {
            int col = nt * 128 + (wv * 2 + cc) * 16 + (lane & 15);
            float bv = by[col];
#pragma unroll
            for (int m = 0; m < 4; ++m)
#pragma unroll
                for (int q = 0; q < 4; ++q) {
                    long row = r0 + m * 16 + ((lane >> 4) << 2) + q;
                    y[row * 1024 + col] = acc[m][cc][q] + bv;
                }
        }
    }
}

// ---------------------------------------------------------------------------
extern "C" void kernel_launch(void* const* d_in, const int* in_sizes, int n_in,
                              void* d_out, int out_size, void* d_ws,
                              size_t ws_size, hipStream_t stream) {
    const float* input = (const float*)d_in[0];
    const float* Wxz = (const float*)d_in[1];
    const float* Whz = (const float*)d_in[2];
    const float* bz  = (const float*)d_in[3];
    const float* Wxr = (const float*)d_in[4];
    const float* Whr = (const float*)d_in[5];
    const float* br  = (const float*)d_in[6];
    const float* Wxg = (const float*)d_in[7];
    const float* Whg = (const float*)d_in[8];
    const float* bg  = (const float*)d_in[9];
    const float* Why = (const float*)d_in[10];
    const float* by  = (const float*)d_in[11];
    (void)in_sizes; (void)n_in; (void)out_size; (void)ws_size;

    float* yreg   = (float*)d_out;            // [64][512][1024] h0/h1/y
    float* hidden = yreg + 33554432;          // [64][2][1024]

    char* ws = (char*)d_ws;
    u32* flags = (u32*)ws;                    //  65536 B
    u16* hbg   = (u16*)(ws + 65536);          // 262144 B
    u16* rbg   = (u16*)(ws + 327680);         // 262144 B

    hipFuncSetAttribute(reinterpret_cast<const void*>(gru_scan),
                        hipFuncAttributeMaxDynamicSharedMemorySize, SCAN_LDS);
    hipFuncSetAttribute(reinterpret_cast<const void*>(ygemm),
                        hipFuncAttributeMaxDynamicSharedMemorySize, YG_LDS);
    hipMemsetAsync(flags, 0, 65536, stream);

    gru_scan<<<256, 512, SCAN_LDS, stream>>>(
        input, Wxz, Wxr, Wxg, Whz, Whr, Whg, bz, br, bg,
        yreg, hidden, hbg, rbg, flags, /*layer=*/0, /*eb=*/0);
    gru_scan<<<256, 512, SCAN_LDS, stream>>>(
        yreg, Wxz, Wxr, Wxg, Whz, Whr, Whg, bz, br, bg,
        yreg, hidden, hbg, rbg, flags, /*layer=*/1, /*eb=*/512);
    ygemm<<<512, 256, YG_LDS, stream>>>(Why, by, yreg);
}